// Round 19
// baseline (75.816 us; speedup 1.0000x reference)
//
#include <hip/hip_runtime.h>
#include <math.h>

#define IN_CH 64
#define OUT_CH 64
#define M1 32
#define M2 32
#define HH 512
#define WW 512

// ---------------- workspace layout (floats) ----------------
// F   : [512][64]  cols 0..31 = cos(2pi k h/512), cols 32..63 = sin(...)
// FA2 : [256][64]  folded stage-A table. col j<32: re, j>=32: im; mode k=kperm(j&31);
//                  value = cos(2pi k w'/512) (re) or -sin (im). kperm(q)= q<16 ? 2q : 2(q-16)+1.
// GE2 : [64][256]  folded stage-E table. row c: c<16 re k=2c; 16..31 im k=2(c-16);
//                  32..47 re k=2(c-32)+1; 48..63 im k=2(c-48)+1. cos (re) / -sin (im).
// GT  : [64][512]  row j<32: cos(2pi j t/512); row j>=32: -sin(...)
// XFp : [64 i][8 ht][2 reim][32 kx][32 ky']  partial h-DFT
// Gp  : [2 ic][64 o][32 kx][32 ky][2]  partial channel-mix (REAL ky order)
static const size_t OFF_F   = 0;
static const size_t OFF_FA2 = 32768;
static const size_t OFF_GE2 = 49152;
static const size_t OFF_GT  = 65536;
static const size_t OFF_XFP = 98304;
static const size_t OFF_GP  = OFF_XFP + (size_t)64*8*2048;

__device__ __forceinline__ void gload16(const float* g, float* l) {
    __builtin_amdgcn_global_load_lds(
        (const __attribute__((address_space(1))) void*)g,
        (__attribute__((address_space(3))) void*)l, 16, 0, 0);
}

__global__ void build_table(float* __restrict__ F, float* __restrict__ FA2,
                            float* __restrict__ GE2, float* __restrict__ GT) {
    int idx = blockIdx.x * 256 + threadIdx.x;      // 0..32767
    const float c0 = 6.283185307179586f / 512.0f;
    {   // F + GT
        int w = idx >> 6, j = idx & 63, k = j & 31;
        int m = (k * w) & 511;
        float s, c;
        sincosf(c0 * (float)m, &s, &c);
        F[idx] = (j < 32) ? c : s;
        GT[(size_t)j * 512 + w] = (j < 32) ? c : -s;
    }
    if (idx < 16384) {   // FA2 [256][64]
        int wp = idx >> 6, j = idx & 63, q = j & 31;
        int k = (q < 16) ? 2 * q : 2 * (q - 16) + 1;
        int m = (k * wp) & 511;
        float s, c;
        sincosf(c0 * (float)m, &s, &c);
        FA2[idx] = (j < 32) ? c : -s;
    }
    if (idx < 16384) {   // GE2 [64][256]
        int cc = idx >> 8, wp = idx & 255;
        int base = cc & 15, parity = (cc >> 5) & 1, isIm = (cc >> 4) & 1;
        int k = 2 * base + parity;
        int m = (k * wp) & 511;
        float s, c;
        sincosf(c0 * (float)m, &s, &c);
        GE2[idx] = isIm ? -s : c;
    }
}

// Fused A+B — R7 geometry, NO global_load_lds (barriers no longer drain vmcnt):
// e/o double-buffered in LDS (one barrier per chunk); x loads issued one full
// chunk ahead into REGISTERS (cross barriers in flight, T14); FA2 read directly
// from VMEM in the inner loop (L1/L2-hot 64KB table, 16x16B broadcast per instr).
// grid 512: i = bid>>3, ht = bid&7 (64 h-rows).
__global__ __launch_bounds__(256) void fusedAB(const float* __restrict__ x,
                                               const float* __restrict__ FA2,
                                               const float* __restrict__ GT,
                                               float* __restrict__ XFp) {
    // two e/o buffers: buf b at xeo + b*8712 { e [64][68] @0, o @4360 }
    // phase B: xw [64][68] @0, gt [64][68] @8712
    __shared__ __align__(16) float xeo[17424];
    int t = threadIdx.x, tx = t & 15, ty = t >> 4;
    int i = blockIdx.x >> 3, ht = blockIdx.x & 7;
    int h0 = ht * 64;

    const float* xbase = &x[((size_t)i * 512 + h0) * 512];
    float4 ra[4], rb[4], gtr[4];
    float acc[4][4] = {};

    // prologue: chunk0 -> regs -> buf0 ; chunk1 -> regs
#pragma unroll
    for (int p = 0; p < 4; ++p) {
        int flat = p * 1024 + t * 4;
        int rl = flat >> 6, c4 = flat & 63;
        const float* xr = xbase + (size_t)rl * 512 + c4;
        ra[p] = *(const float4*)xr;
        rb[p] = *(const float4*)(xr + 256);
    }
#pragma unroll
    for (int p = 0; p < 4; ++p) {
        int flat = p * 1024 + t * 4;
        int rl = flat >> 6, c4 = flat & 63;
        *(float4*)&xeo[rl * 68 + c4] =
            make_float4(ra[p].x + rb[p].x, ra[p].y + rb[p].y,
                        ra[p].z + rb[p].z, ra[p].w + rb[p].w);
        *(float4*)&xeo[4360 + rl * 68 + c4] =
            make_float4(ra[p].x - rb[p].x, ra[p].y - rb[p].y,
                        ra[p].z - rb[p].z, ra[p].w - rb[p].w);
        const float* xr = xbase + (size_t)rl * 512 + 64 + c4;
        ra[p] = *(const float4*)xr;
        rb[p] = *(const float4*)(xr + 256);
    }
    __syncthreads();                 // buf0 ready

#pragma unroll
    for (int tt = 0; tt < 4; ++tt) {
        float* wb = &xeo[((tt + 1) & 1) * 8712];
        const float* rbf = &xeo[(tt & 1) * 8712];
        if (tt < 3) {                // write chunk tt+1 (regs), prefetch tt+2
#pragma unroll
            for (int p = 0; p < 4; ++p) {
                int flat = p * 1024 + t * 4;
                int rl = flat >> 6, c4 = flat & 63;
                *(float4*)&wb[rl * 68 + c4] =
                    make_float4(ra[p].x + rb[p].x, ra[p].y + rb[p].y,
                                ra[p].z + rb[p].z, ra[p].w + rb[p].w);
                *(float4*)&wb[4360 + rl * 68 + c4] =
                    make_float4(ra[p].x - rb[p].x, ra[p].y - rb[p].y,
                                ra[p].z - rb[p].z, ra[p].w - rb[p].w);
                if (tt < 2) {
                    const float* xr = xbase + (size_t)rl * 512 + (tt + 2) * 64 + c4;
                    ra[p] = *(const float4*)xr;
                    rb[p] = *(const float4*)(xr + 256);
                }
            }
            if (tt == 2) {           // prefetch GT slice for phase B
#pragma unroll
                for (int p = 0; p < 4; ++p) {
                    int flat = p * 1024 + t * 4;
                    gtr[p] = *(const float4*)&GT[(size_t)(flat >> 6) * 512 + h0 + (flat & 63)];
                }
            }
        }
        // compute chunk tt: A from LDS, B (FA2) from VMEM
        const float* xsb = rbf + ((tx & 4) ? 4360 : 0);
        const float* fa2c = FA2 + (size_t)tt * 4096 + tx * 4;
#pragma unroll 4
        for (int k0 = 0; k0 < 64; k0 += 4) {
            float4 av[4], bv[4];
#pragma unroll
            for (int r = 0; r < 4; ++r)
                av[r] = *(const float4*)&xsb[(ty * 4 + r) * 68 + k0];
#pragma unroll
            for (int kk = 0; kk < 4; ++kk)
                bv[kk] = *(const float4*)(fa2c + (size_t)(k0 + kk) * 64);
#pragma unroll
            for (int kk = 0; kk < 4; ++kk)
#pragma unroll
                for (int r = 0; r < 4; ++r) {
                    float xk = (kk == 0) ? av[r].x : (kk == 1) ? av[r].y
                             : (kk == 2) ? av[r].z : av[r].w;
                    acc[r][0] = __builtin_fmaf(xk, bv[kk].x, acc[r][0]);
                    acc[r][1] = __builtin_fmaf(xk, bv[kk].y, acc[r][1]);
                    acc[r][2] = __builtin_fmaf(xk, bv[kk].z, acc[r][2]);
                    acc[r][3] = __builtin_fmaf(xk, bv[kk].w, acc[r][3]);
                }
        }
        __syncthreads();             // readers of rbf done; wb visible
    }

    // epilogue: xw -> xeo[0..] ([64][68]); gt regs -> xeo[8712..] ([64][68])
#pragma unroll
    for (int r = 0; r < 4; ++r)
        *(float4*)&xeo[(ty * 4 + r) * 68 + tx * 4] =
            make_float4(acc[r][0], acc[r][1], acc[r][2], acc[r][3]);
#pragma unroll
    for (int p = 0; p < 4; ++p) {
        int flat = p * 1024 + t * 4;
        int j = flat >> 6, c4 = flat & 63;
        *(float4*)&xeo[8712 + j * 68 + c4] = gtr[p];
    }
    __syncthreads();

    // Phase B (R7 pattern; gt at xeo+8712)
    const float* gtb = &xeo[8712];
    int kx = t >> 3, kg = t & 7;
    float rr[4] = {0.f, 0.f, 0.f, 0.f};
    float ii[4] = {0.f, 0.f, 0.f, 0.f};
#pragma unroll 4
    for (int hh = 0; hh < 64; ++hh) {
        float cv = gtb[kx * 68 + hh];
        float sv = gtb[(kx + 32) * 68 + hh];         // = -sin
        float4 xr4 = *(const float4*)&xeo[hh * 68 + kg * 4];
        float4 xi4 = *(const float4*)&xeo[hh * 68 + 32 + kg * 4];
        rr[0] = __builtin_fmaf(xr4.x, cv, rr[0]); rr[0] = __builtin_fmaf(xi4.x, -sv, rr[0]);
        rr[1] = __builtin_fmaf(xr4.y, cv, rr[1]); rr[1] = __builtin_fmaf(xi4.y, -sv, rr[1]);
        rr[2] = __builtin_fmaf(xr4.z, cv, rr[2]); rr[2] = __builtin_fmaf(xi4.z, -sv, rr[2]);
        rr[3] = __builtin_fmaf(xr4.w, cv, rr[3]); rr[3] = __builtin_fmaf(xi4.w, -sv, rr[3]);
        ii[0] = __builtin_fmaf(xi4.x, cv, ii[0]); ii[0] = __builtin_fmaf(xr4.x, sv, ii[0]);
        ii[1] = __builtin_fmaf(xi4.y, cv, ii[1]); ii[1] = __builtin_fmaf(xr4.y, sv, ii[1]);
        ii[2] = __builtin_fmaf(xi4.z, cv, ii[2]); ii[2] = __builtin_fmaf(xr4.z, sv, ii[2]);
        ii[3] = __builtin_fmaf(xi4.w, cv, ii[3]); ii[3] = __builtin_fmaf(xr4.w, sv, ii[3]);
    }
    size_t base = ((size_t)i * 8 + ht) * 2048;
    *(float4*)&XFp[base + t * 4]        = make_float4(rr[0], rr[1], rr[2], rr[3]);
    *(float4*)&XFp[base + 1024 + t * 4] = make_float4(ii[0], ii[1], ii[2], ii[3]);
}

// Stage C: partial channel mix, i split in 2. grid 512. float4 ht-sum. (R16 verbatim)
__global__ __launch_bounds__(256) void stageC(const float* __restrict__ XFp,
                                              const float* __restrict__ Wr,
                                              const float* __restrict__ Wi,
                                              float* __restrict__ Gp) {
    __shared__ float sxr[32][33];   // [ky'][i']
    __shared__ float sxi[32][33];
    int t = threadIdx.x;
    int kx = blockIdx.x & 31, oc = (blockIdx.x >> 5) & 7, ic = blockIdx.x >> 8;
    {
        int ip = t >> 3, kys4 = t & 7;       // ip 0..31, ky'-quad 0..7
        int i = ic * 32 + ip;
        float4 sr = make_float4(0.f, 0.f, 0.f, 0.f);
        float4 si = make_float4(0.f, 0.f, 0.f, 0.f);
#pragma unroll
        for (int ht = 0; ht < 8; ++ht) {
            size_t base = ((size_t)i * 8 + ht) * 2048 + kx * 32 + kys4 * 4;
            float4 r4 = *(const float4*)&XFp[base];
            float4 i4 = *(const float4*)&XFp[base + 1024];
            sr.x += r4.x; sr.y += r4.y; sr.z += r4.z; sr.w += r4.w;
            si.x += i4.x; si.y += i4.y; si.z += i4.z; si.w += i4.w;
        }
        sxr[kys4 * 4 + 0][ip] = sr.x; sxr[kys4 * 4 + 1][ip] = sr.y;
        sxr[kys4 * 4 + 2][ip] = sr.z; sxr[kys4 * 4 + 3][ip] = sr.w;
        sxi[kys4 * 4 + 0][ip] = si.x; sxi[kys4 * 4 + 1][ip] = si.y;
        sxi[kys4 * 4 + 2][ip] = si.z; sxi[kys4 * 4 + 3][ip] = si.w;
    }
    __syncthreads();
    int ky = t & 31, ol = t >> 5;            // REAL ky
    int kyp = (ky & 1) ? 16 + (ky >> 1) : (ky >> 1);
    int o = oc * 8 + ol;
    float lr = 0.f, li = 0.f;
#pragma unroll 4
    for (int ip = 0; ip < 32; ++ip) {
        float a = sxr[kyp][ip];
        float b = sxi[kyp][ip];
        size_t widx = ((size_t)(ic * 32 + ip) * 64 + o) * 1024 + kx * 32 + ky;
        float wrv = Wr[widx];
        float wiv = Wi[widx];
        lr = __builtin_fmaf(a, wrv, lr); lr = __builtin_fmaf(-b, wiv, lr);
        li = __builtin_fmaf(a, wiv, li); li = __builtin_fmaf(b, wrv, li);
    }
    size_t gidx = ((size_t)ic * 65536 + (size_t)o * 1024 + kx * 32 + ky) * 2;
    Gp[gidx]     = lr;
    Gp[gidx + 1] = li;
}

// Fused (reduceG +) D + E. grid 512: o = bid>>3, ht = bid&7. (R16 verbatim)
__global__ __launch_bounds__(256) void fusedDE(const float* __restrict__ Fc,
                                               const float* __restrict__ Gp,
                                               const float* __restrict__ GE2,
                                               float* __restrict__ out) {
    __shared__ __align__(16) float as[4096];   // F-tile (src-swizzled), then Z (XOR-swizzled)
    __shared__ __align__(16) float bs[4096];   // G [64m][64j'], then GE2 tiles
    int t = threadIdx.x, tx = t & 15, ty = t >> 4;
    int o = blockIdx.x >> 3, ht = blockIdx.x & 7;
    int sw = (ty & 3) << 2;

    const float2* gp2 = (const float2*)Gp;
#pragma unroll
    for (int q = 0; q < 4; ++q) {
        int iq = q * 256 + t;                 // 0..1023 = kx*32+ky (REAL ky)
        int ky = iq & 31, kx = iq >> 5;
        float2 g0 = gp2[(size_t)o * 1024 + iq];
        float2 g1 = gp2[(size_t)65536 + (size_t)o * 1024 + iq];
        float sc = ((ky == 0) ? 1.0f : 2.0f) * (1.0f / 262144.0f);
        float lr = (g0.x + g1.x) * sc;
        float li = (g0.y + g1.y) * sc;
        int pp = ky & 1, qq = ky >> 1;
        int colR = pp * 32 + qq, colI = pp * 32 + 16 + qq;
        bs[kx * 64 + colR]        = lr;
        bs[(32 + kx) * 64 + colR] = -li;
        bs[kx * 64 + colI]        = li;
        bs[(32 + kx) * 64 + colI] = lr;
    }
#pragma unroll
    for (int p = 0; p < 4; ++p) {
        int flat = p * 1024 + t * 4;
        int s16 = flat >> 2;
        int row = s16 >> 4, cp = s16 & 15;
        int cg = cp ^ ((row >> 2) & 3);
        gload16(Fc + (size_t)(ht * 64 + row) * 64 + cg * 4, &as[flat]);
    }
    __syncthreads();

    float acc[4][4] = {};
#pragma unroll 4
    for (int k0 = 0; k0 < 64; k0 += 4) {
        int ka = k0 ^ sw;
        float4 av[4], bv[4];
#pragma unroll
        for (int r = 0; r < 4; ++r)
            av[r] = *(const float4*)&as[(ty * 4 + r) * 64 + ka];
#pragma unroll
        for (int kk = 0; kk < 4; ++kk)
            bv[kk] = *(const float4*)&bs[(k0 + kk) * 64 + tx * 4];
#pragma unroll
        for (int kk = 0; kk < 4; ++kk)
#pragma unroll
            for (int r = 0; r < 4; ++r) {
                float xk = (kk == 0) ? av[r].x : (kk == 1) ? av[r].y
                         : (kk == 2) ? av[r].z : av[r].w;
                acc[r][0] = __builtin_fmaf(xk, bv[kk].x, acc[r][0]);
                acc[r][1] = __builtin_fmaf(xk, bv[kk].y, acc[r][1]);
                acc[r][2] = __builtin_fmaf(xk, bv[kk].z, acc[r][2]);
                acc[r][3] = __builtin_fmaf(xk, bv[kk].w, acc[r][3]);
            }
    }
    __syncthreads();

#pragma unroll
    for (int r = 0; r < 4; ++r) {
        int row = ty * 4 + r;
        int cg = tx ^ ((row >> 2) & 3);
        *(float4*)&as[row * 64 + cg * 4] =
            make_float4(acc[r][0], acc[r][1], acc[r][2], acc[r][3]);
    }

    for (int cb = 0; cb < 4; ++cb) {
        __syncthreads();
#pragma unroll
        for (int p = 0; p < 4; ++p) {
            int flat = p * 1024 + t * 4;
            int brow = flat >> 6, bcol = flat & 63;
            gload16(GE2 + (size_t)brow * 256 + cb * 64 + bcol, &bs[flat]);
        }
        __syncthreads();
        float pa[4][4] = {}, pb[4][4] = {};
#pragma unroll 4
        for (int k0 = 0; k0 < 32; k0 += 4) {
            int kae = k0 ^ sw, kao = 32 + (k0 ^ sw);
            float4 av[4], bv[4], aw[4], bw[4];
#pragma unroll
            for (int r = 0; r < 4; ++r) {
                av[r] = *(const float4*)&as[(ty * 4 + r) * 64 + kae];
                aw[r] = *(const float4*)&as[(ty * 4 + r) * 64 + kao];
            }
#pragma unroll
            for (int kk = 0; kk < 4; ++kk) {
                bv[kk] = *(const float4*)&bs[(k0 + kk) * 64 + tx * 4];
                bw[kk] = *(const float4*)&bs[(32 + k0 + kk) * 64 + tx * 4];
            }
#pragma unroll
            for (int kk = 0; kk < 4; ++kk)
#pragma unroll
                for (int r = 0; r < 4; ++r) {
                    float xe = (kk == 0) ? av[r].x : (kk == 1) ? av[r].y
                             : (kk == 2) ? av[r].z : av[r].w;
                    float xo = (kk == 0) ? aw[r].x : (kk == 1) ? aw[r].y
                             : (kk == 2) ? aw[r].z : aw[r].w;
                    pa[r][0] = __builtin_fmaf(xe, bv[kk].x, pa[r][0]);
                    pa[r][1] = __builtin_fmaf(xe, bv[kk].y, pa[r][1]);
                    pa[r][2] = __builtin_fmaf(xe, bv[kk].z, pa[r][2]);
                    pa[r][3] = __builtin_fmaf(xe, bv[kk].w, pa[r][3]);
                    pb[r][0] = __builtin_fmaf(xo, bw[kk].x, pb[r][0]);
                    pb[r][1] = __builtin_fmaf(xo, bw[kk].y, pb[r][1]);
                    pb[r][2] = __builtin_fmaf(xo, bw[kk].z, pb[r][2]);
                    pb[r][3] = __builtin_fmaf(xo, bw[kk].w, pb[r][3]);
                }
        }
#pragma unroll
        for (int r = 0; r < 4; ++r) {
            float* orow = out + (size_t)(o * 512 + ht * 64 + ty * 4 + r) * 512;
            *(float4*)&orow[cb * 64 + tx * 4] =
                make_float4(pa[r][0] + pb[r][0], pa[r][1] + pb[r][1],
                            pa[r][2] + pb[r][2], pa[r][3] + pb[r][3]);
            *(float4*)&orow[256 + cb * 64 + tx * 4] =
                make_float4(pa[r][0] - pb[r][0], pa[r][1] - pb[r][1],
                            pa[r][2] - pb[r][2], pa[r][3] - pb[r][3]);
        }
    }
}

extern "C" void kernel_launch(void* const* d_in, const int* in_sizes, int n_in,
                              void* d_out, int out_size, void* d_ws, size_t ws_size,
                              hipStream_t stream) {
    const float* x  = (const float*)d_in[0];
    const float* Wr = (const float*)d_in[1];
    const float* Wi = (const float*)d_in[2];
    float* out = (float*)d_out;
    float* ws  = (float*)d_ws;

    float* F   = ws + OFF_F;
    float* FA2 = ws + OFF_FA2;
    float* GE2 = ws + OFF_GE2;
    float* GT  = ws + OFF_GT;
    float* XFp = ws + OFF_XFP;
    float* Gp  = ws + OFF_GP;

    build_table<<<128, 256, 0, stream>>>(F, FA2, GE2, GT);
    fusedAB<<<512, 256, 0, stream>>>(x, FA2, GT, XFp);
    stageC<<<512, 256, 0, stream>>>(XFp, Wr, Wi, Gp);
    fusedDE<<<512, 256, 0, stream>>>(F, Gp, GE2, out);
}